// Round 7
// baseline (284.409 us; speedup 1.0000x reference)
//
#include <hip/hip_runtime.h>

// Problem constants: B=4, C=2048, D=1024, HEAD=16, HD=64, STRIDE=4, KC=512
#define EPSF 1.1920929e-07f
#define QSCALE 0.18033688011112042f  // log2(e)/8
#define SMAX 12.0f                   // score bound in exp2 domain: 64*log2(e)/8 = 11.54 < 12

typedef _Float16 hf;
typedef __attribute__((ext_vector_type(4))) _Float16 h4;
typedef __attribute__((ext_vector_type(8))) _Float16 h8;
typedef __attribute__((ext_vector_type(4))) float fx4;

#define DEVI __device__ __forceinline__

DEVI void async16(const void* g, void* l) {
  __builtin_amdgcn_global_load_lds((const __attribute__((address_space(1))) unsigned int*)g,
                                   (__attribute__((address_space(3))) unsigned int*)l, 16, 0, 0);
}

DEVI fx4 mfma16(h4 a, h4 b, fx4 c) {
  return __builtin_amdgcn_mfma_f32_16x16x16f16(a, b, c, 0, 0, 0);
}
DEVI fx4 mfma32(h8 a, h8 b, fx4 c) {
  return __builtin_amdgcn_mfma_f32_16x16x32_f16(a, b, c, 0, 0, 0);
}

// LDS tiles: [row][64 hf] = 128B rows, XOR-swizzled at 16B granularity (GEMM only).
DEVI h8 ld16(const hf* base, int row, int g16) {
  int off = (row * 128 + (g16 << 4)) ^ ((row & 7) << 4);
  return *(const h8*)((const char*)base + off);
}

// ---------------- weight cast + transpose: W[K][N] f32 -> Wt[N][K] f16 ----------
__global__ __launch_bounds__(256) void k_wcast(const float* __restrict__ W, hf* __restrict__ Wt,
                                               int K, int N) {
  __shared__ float ls[64][65];
  int kt = blockIdx.x, nt = blockIdx.y, t = threadIdx.x;
  int c4 = (t & 15) * 4, r0 = t >> 4;
#pragma unroll
  for (int i = 0; i < 4; ++i) {
    int row = i * 16 + r0;
    fx4 v = *(const fx4*)(W + (size_t)(kt * 64 + row) * N + nt * 64 + c4);
    ls[row][c4 + 0] = v[0]; ls[row][c4 + 1] = v[1];
    ls[row][c4 + 2] = v[2]; ls[row][c4 + 3] = v[3];
  }
  __syncthreads();
  int cc = t >> 4, kk4 = (t & 15) * 4;
#pragma unroll
  for (int i = 0; i < 4; ++i) {
    int nn = i * 16 + cc;
    h4 p = {(hf)ls[kk4 + 0][nn], (hf)ls[kk4 + 1][nn], (hf)ls[kk4 + 2][nn], (hf)ls[kk4 + 3][nn]};
    *(h4*)(Wt + (size_t)(nt * 64 + nn) * K + kt * 64 + kk4) = p;
  }
}

// ---------------- rope table: tab[t][j] = (cos, sin) interleaved, 2048 x 32 -----
__global__ __launch_bounds__(256) void k_table(float* __restrict__ tab) {
  int idx = blockIdx.x * 256 + threadIdx.x;  // 65536
  int tt = idx >> 5, j = idx & 31;
  double e = pow(21.0, (double)j / 31.0) - 1.0;   // 10^(j*log10(21)/31) - 1
  float bf = (float)(0.2 * e);
  float fr = (float)tt * bf;                       // fp32 product like reference
  double d = (double)fr;
  float2 cs = make_float2((float)cos(d), (float)sin(d));
  ((float2*)tab)[idx] = cs;
}

// ---------------- dual rmsnorm (shared mean-square), compact kv rows ------------
__global__ __launch_bounds__(256) void k_dualnorm(const float* __restrict__ x,
                                                  const float* __restrict__ wq,
                                                  const float* __restrict__ wkv,
                                                  hf* __restrict__ xqn, hf* __restrict__ xkvc) {
  int row = blockIdx.x, t = threadIdx.x;
  const fx4* xr = (const fx4*)(x + (size_t)row * 1024);
  fx4 v = xr[t];
  float ss = v[0] * v[0] + v[1] * v[1] + v[2] * v[2] + v[3] * v[3];
#pragma unroll
  for (int m = 1; m <= 32; m <<= 1) ss += __shfl_xor(ss, m);
  __shared__ float red[4];
  if ((t & 63) == 0) red[t >> 6] = ss;
  __syncthreads();
  float r = rsqrtf((red[0] + red[1] + red[2] + red[3]) * (1.0f / 1024.0f) + EPSF);
  fx4 a = ((const fx4*)wq)[t];
  h4 oq = {(hf)(v[0] * r * a[0]), (hf)(v[1] * r * a[1]), (hf)(v[2] * r * a[2]), (hf)(v[3] * r * a[3])};
  *(h4*)(xqn + (size_t)row * 1024 + t * 4) = oq;
  int c = row & 2047;
  if ((c & 3) == 0) {
    fx4 bk = ((const fx4*)wkv)[t];
    int crow = (row >> 11) * 512 + (c >> 2);
    h4 ok = {(hf)(v[0] * r * bk[0]), (hf)(v[1] * r * bk[1]), (hf)(v[2] * r * bk[2]), (hf)(v[3] * r * bk[3])};
    *(h4*)(xkvc + (size_t)crow * 1024 + t * 4) = ok;
  }
}

// ---------------- GEMM: out[M][N] = A[M][K] @ Bt[N][K]^T + bias ------------------
// 128x128 tile, BK=64, 16x16x32 MFMA, double-buffered LDS, counted-vmcnt 2-phase.
// EPI 0: f16 row-major   EPI 1: kv special (k half row-major, v half -> vT)   EPI 2: f32 row-major
template <int EPI>
__global__ __launch_bounds__(256) void k_gemm(const hf* __restrict__ A, const hf* __restrict__ Bt,
                                              const float* __restrict__ bias, void* __restrict__ outp,
                                              int M, int N, int K, int MB, hf* __restrict__ vt) {
  __shared__ alignas(16) hf lsA[2][128 * 64];
  __shared__ alignas(16) hf lsB[2][128 * 64];
  int t = threadIdx.x, l = t & 63, w = t >> 6, grp = l >> 4, ln = l & 15;
  int bm = blockIdx.x % MB, bn = blockIdx.x / MB;
  int m0 = bm * 128, n0 = bn * 128;
  int wr = w >> 1, wc = w & 1;
  fx4 acc[4][4] = {};
  int nkt = K >> 6;

  auto stage = [&](int kt, int b) {
    int k0 = kt << 6;
#pragma unroll
    for (int p = 0; p < 4; ++p) {
      int ci = p * 256 + t;
      int row = ci >> 3, g = (ci & 7) ^ (row & 7);
      async16(A + (size_t)(m0 + row) * K + k0 + g * 8, (char*)lsA[b] + p * 4096 + w * 1024);
    }
#pragma unroll
    for (int p = 0; p < 4; ++p) {
      int ci = p * 256 + t;
      int row = ci >> 3, g = (ci & 7) ^ (row & 7);
      async16(Bt + (size_t)(n0 + row) * K + k0 + g * 8, (char*)lsB[b] + p * 4096 + w * 1024);
    }
  };

  stage(0, 0);
  for (int kt = 0; kt < nkt; ++kt) {
    int cur = kt & 1;
    if (kt + 1 < nkt) {
      stage(kt + 1, cur ^ 1);
      asm volatile("s_waitcnt vmcnt(8)" ::: "memory");  // current tile landed; next stays in flight
    } else {
      asm volatile("s_waitcnt vmcnt(0)" ::: "memory");
    }
    __builtin_amdgcn_s_barrier();
    __builtin_amdgcn_sched_barrier(0);
    __builtin_amdgcn_s_setprio(1);
#pragma unroll
    for (int kk = 0; kk < 2; ++kk) {
      h8 af[4], bf[4];
#pragma unroll
      for (int i = 0; i < 4; ++i) af[i] = ld16(lsA[cur], wr * 64 + i * 16 + ln, kk * 4 + grp);
#pragma unroll
      for (int i = 0; i < 4; ++i) bf[i] = ld16(lsB[cur], wc * 64 + i * 16 + ln, kk * 4 + grp);
#pragma unroll
      for (int mi = 0; mi < 4; ++mi)
#pragma unroll
        for (int ni = 0; ni < 4; ++ni)
          acc[mi][ni] = mfma32(af[mi], bf[ni], acc[mi][ni]);
    }
    __builtin_amdgcn_s_setprio(0);
    __builtin_amdgcn_sched_barrier(0);
    __builtin_amdgcn_s_barrier();  // WAR: all waves done reading buf[cur] before next overwrite
  }
#pragma unroll
  for (int ni = 0; ni < 4; ++ni) {
    int n = n0 + wc * 64 + ni * 16 + ln;
    float bs = bias[n];
#pragma unroll
    for (int mi = 0; mi < 4; ++mi) {
      int mb_ = m0 + wr * 64 + mi * 16 + grp * 4;
      fx4 v = acc[mi][ni];
      v += bs;
      if constexpr (EPI == 2) {
        float* O = (float*)outp;
#pragma unroll
        for (int r = 0; r < 4; ++r) O[(size_t)(mb_ + r) * N + n] = v[r];
      } else if constexpr (EPI == 0) {
        hf* O = (hf*)outp;
#pragma unroll
        for (int r = 0; r < 4; ++r) O[(size_t)(mb_ + r) * N + n] = (hf)v[r];
      } else {
        if (n < 1024) {  // k half, row-major [2048][1024]
          hf* O = (hf*)outp;
#pragma unroll
          for (int r = 0; r < 4; ++r) O[(size_t)(mb_ + r) * 1024 + n] = (hf)v[r];
        } else {  // v half -> vT[b,h][hd][kc]
          int nv = n - 1024, h = nv >> 6, hd = nv & 63;
          int b = m0 >> 9, kc0 = mb_ & 511;
          h4 pk = {(hf)v[0], (hf)v[1], (hf)v[2], (hf)v[3]};
          *(h4*)(vt + ((size_t)(b * 16 + h) * 64 + hd) * 512 + kc0) = pk;
        }
      }
    }
  }
}

// ---------------- rope + per-head rmsnorm + transpose (q and k variants) --------
template <bool ISQ>
__global__ __launch_bounds__(256) void k_post(const hf* __restrict__ raw, const float* __restrict__ lnw,
                                              const float* __restrict__ tab, hf* __restrict__ outn) {
  int row = blockIdx.x, t = threadIdx.x;
  int h = t >> 4, hd0 = (t & 15) * 4;
  h4 q = ((const h4*)(raw + (size_t)row * 1024))[t];
  float q0 = (float)q[0], q1 = (float)q[1], q2 = (float)q[2], q3 = (float)q[3];
  float ss = q0 * q0 + q1 * q1 + q2 * q2 + q3 * q3;
  ss += __shfl_xor(ss, 1); ss += __shfl_xor(ss, 2);
  ss += __shfl_xor(ss, 4); ss += __shfl_xor(ss, 8);
  // rope preserves pair norms -> ms computable pre-rotation
  float scl = rsqrtf(ss * (1.0f / 64.0f) + EPSF);
  if (ISQ) scl *= QSCALE;
  int b, c, seq;
  if (ISQ) { b = row >> 11; c = row & 2047; seq = c; }
  else     { b = row >> 9;  c = row & 511;  seq = c * 4; }
  fx4 cs = *(const fx4*)(tab + (size_t)seq * 64 + hd0);
  float o0 = q0 * cs[0] - q1 * cs[1];
  float o1 = q0 * cs[1] + q1 * cs[0];
  float o2 = q2 * cs[2] - q3 * cs[3];
  float o3 = q2 * cs[3] + q3 * cs[2];
  fx4 lw = *(const fx4*)(lnw + hd0);
  h4 o = {(hf)(o0 * lw[0] * scl), (hf)(o1 * lw[1] * scl), (hf)(o2 * lw[2] * scl), (hf)(o3 * lw[3] * scl)};
  int rows = ISQ ? 2048 : 512;
  *(h4*)(outn + ((size_t)(b * 16 + h) * rows + c) * 64 + hd0) = o;
}

// ---------------- attention v2: no LDS, no barriers, fixed-max softmax ----------
// K/V per plane = 128KB; XCD swizzle keeps 8 planes (1MB) per XCD L2; the 4 waves
// of a block share the same 32KB chunk -> L1 hits. Scores (exp2 domain) bounded by
// 64*log2e/8 = 11.54 < SMAX=12, so p = exp2(s-12) needs no online max/rescale;
// l-reduction deferred to a single shfl pair at the end.
__global__ __launch_bounds__(256) void k_attn(const hf* __restrict__ qn, const hf* __restrict__ kn,
                                              const hf* __restrict__ vt, hf* __restrict__ a) {
  int t = threadIdx.x, l = t & 63, w = t >> 6, grp = l >> 4, ln = l & 15;
  int tile = (blockIdx.x & 7) * (gridDim.x >> 3) + (blockIdx.x >> 3);  // XCD-bijective
  int bq = tile & 15, plane = tile >> 4;
  const hf* qp = qn + (size_t)plane * 2048 * 64;
  const hf* kp = kn + (size_t)plane * 512 * 64;
  const hf* vp = vt + (size_t)plane * 64 * 512;
  int q0 = bq * 128 + w * 32;

  h8 qf[2][2];
#pragma unroll
  for (int mf = 0; mf < 2; ++mf)
#pragma unroll
    for (int kk = 0; kk < 2; ++kk)
      qf[mf][kk] = *(const h8*)(qp + (size_t)(q0 + mf * 16 + ln) * 64 + kk * 32 + grp * 8);

  fx4 o[4][2] = {};
  float lsum[2] = {0.f, 0.f};

  for (int ch = 0; ch < 8; ++ch) {
    int kc0 = ch * 64;

    // QK^T: s[kt][mf] holds S[key = kt*16+grp*4+j][q = ln]
    fx4 s[4][2] = {};
#pragma unroll
    for (int kk = 0; kk < 2; ++kk) {
      h8 kf[4];
#pragma unroll
      for (int kt = 0; kt < 4; ++kt)
        kf[kt] = *(const h8*)(kp + (size_t)(kc0 + kt * 16 + ln) * 64 + kk * 32 + grp * 8);
#pragma unroll
      for (int kt = 0; kt < 4; ++kt)
#pragma unroll
        for (int mf = 0; mf < 2; ++mf)
          s[kt][mf] = mfma32(kf[kt], qf[mf][kk], s[kt][mf]);
    }

    // fixed-max softmax: pure elementwise, no cross-lane traffic
    h4 pf[4][2];
#pragma unroll
    for (int kt = 0; kt < 4; ++kt)
#pragma unroll
      for (int mf = 0; mf < 2; ++mf) {
        fx4 sv = s[kt][mf];
        float e0 = __builtin_amdgcn_exp2f(sv[0] - SMAX);
        float e1 = __builtin_amdgcn_exp2f(sv[1] - SMAX);
        float e2 = __builtin_amdgcn_exp2f(sv[2] - SMAX);
        float e3 = __builtin_amdgcn_exp2f(sv[3] - SMAX);
        lsum[mf] += (e0 + e1) + (e2 + e3);
        h4 tp = {(hf)e0, (hf)e1, (hf)e2, (hf)e3};
        pf[kt][mf] = tp;
      }

    // PV: o[nh][mf] += V^T-frag x P-frag (P layout natively matches mfma16 B)
#pragma unroll
    for (int ks = 0; ks < 4; ++ks) {
      h4 vf[4];
#pragma unroll
      for (int nh = 0; nh < 4; ++nh)
        vf[nh] = *(const h4*)(vp + (size_t)(nh * 16 + ln) * 512 + kc0 + ks * 16 + grp * 4);
#pragma unroll
      for (int nh = 0; nh < 4; ++nh)
#pragma unroll
        for (int mf = 0; mf < 2; ++mf)
          o[nh][mf] = mfma16(vf[nh], pf[ks][mf], o[nh][mf]);
    }
  }

  int b = plane >> 4, h = plane & 15;
#pragma unroll
  for (int mf = 0; mf < 2; ++mf) {
    float p2 = lsum[mf];
    p2 += __shfl_xor(p2, 16);
    p2 += __shfl_xor(p2, 32);
    float inv = 1.0f / p2;
    int cpos = q0 + mf * 16 + ln;
    size_t rowo = ((size_t)b * 2048 + cpos) * 1024;
#pragma unroll
    for (int nh = 0; nh < 4; ++nh) {
      h4 pk = {(hf)(o[nh][mf][0] * inv), (hf)(o[nh][mf][1] * inv),
               (hf)(o[nh][mf][2] * inv), (hf)(o[nh][mf][3] * inv)};
      *(h4*)(a + rowo + h * 64 + nh * 16 + grp * 4) = pk;
    }
  }
}

extern "C" void kernel_launch(void* const* d_in, const int* in_sizes, int n_in,
                              void* d_out, int out_size, void* d_ws, size_t ws_size,
                              hipStream_t stream) {
  (void)in_sizes; (void)n_in; (void)out_size; (void)ws_size;
  const float* x      = (const float*)d_in[0];
  const float* rmsq_w = (const float*)d_in[1];
  const float* q_w    = (const float*)d_in[2];
  const float* q_b    = (const float*)d_in[3];
  const float* rmskv_w= (const float*)d_in[4];
  const float* kv_w   = (const float*)d_in[5];
  const float* kv_b   = (const float*)d_in[6];
  const float* ln_w   = (const float*)d_in[7];
  const float* out_w  = (const float*)d_in[8];
  const float* out_b  = (const float*)d_in[9];

  char* ws = (char*)d_ws;
  hf* wqT   = (hf*)(ws + (size_t)0);           // 2 MB  [1024][1024]
  hf* wkvT  = (hf*)(ws + ((size_t)2 << 20));   // 4 MB  [2048][1024]
  hf* woT   = (hf*)(ws + ((size_t)6 << 20));   // 2 MB
  float* tab= (float*)(ws + ((size_t)8 << 20));// 0.5 MB
  hf* xqn   = (hf*)(ws + ((size_t)9 << 20));   // 16 MB, reused as qn
  hf* qn    = xqn;
  hf* xkvc  = (hf*)(ws + ((size_t)25 << 20));  // 4 MB
  hf* qraw  = (hf*)(ws + ((size_t)29 << 20));  // 16 MB, reused as attn out
  hf* abuf  = qraw;
  hf* kraw  = (hf*)(ws + ((size_t)45 << 20));  // 4 MB
  hf* kn    = (hf*)(ws + ((size_t)49 << 20));  // 4 MB
  hf* vt    = (hf*)(ws + ((size_t)53 << 20));  // 4 MB

  k_wcast<<<dim3(16, 16), 256, 0, stream>>>(q_w,   wqT,  1024, 1024);
  k_wcast<<<dim3(16, 32), 256, 0, stream>>>(kv_w,  wkvT, 1024, 2048);
  k_wcast<<<dim3(16, 16), 256, 0, stream>>>(out_w, woT,  1024, 1024);
  k_table<<<256, 256, 0, stream>>>(tab);
  k_dualnorm<<<8192, 256, 0, stream>>>(x, rmsq_w, rmskv_w, xqn, xkvc);
  k_gemm<0><<<64 * 8, 256, 0, stream>>>(xqn, wqT, q_b, qraw, 8192, 1024, 1024, 64, nullptr);
  k_gemm<1><<<16 * 16, 256, 0, stream>>>(xkvc, wkvT, kv_b, kraw, 2048, 2048, 1024, 16, vt);
  k_post<true><<<8192, 256, 0, stream>>>(qraw, ln_w, tab, qn);
  k_post<false><<<2048, 256, 0, stream>>>(kraw, ln_w, tab, kn);
  k_attn<<<1024, 256, 0, stream>>>(qn, kn, vt, abuf);
  k_gemm<2><<<64 * 8, 256, 0, stream>>>(abuf, woT, out_b, d_out, 8192, 1024, 1024, 64, nullptr);
}

// Round 8
// 227.994 us; speedup vs baseline: 1.2474x; 1.2474x over previous
//
#include <hip/hip_runtime.h>

// Problem constants: B=4, C=2048, D=1024, HEAD=16, HD=64, STRIDE=4, KC=512
#define EPSF 1.1920929e-07f
#define QSCALE 0.18033688011112042f  // log2(e)/8
#define SMAX 12.0f                   // score bound in exp2 domain: 64*log2(e)/8 = 11.54 < 12

typedef _Float16 hf;
typedef __attribute__((ext_vector_type(4))) _Float16 h4;
typedef __attribute__((ext_vector_type(8))) _Float16 h8;
typedef __attribute__((ext_vector_type(4))) float fx4;

#define DEVI __device__ __forceinline__

DEVI void async16(const void* g, void* l) {
  __builtin_amdgcn_global_load_lds((const __attribute__((address_space(1))) unsigned int*)g,
                                   (__attribute__((address_space(3))) unsigned int*)l, 16, 0, 0);
}

DEVI fx4 mfma16(h4 a, h4 b, fx4 c) {
  return __builtin_amdgcn_mfma_f32_16x16x16f16(a, b, c, 0, 0, 0);
}
DEVI fx4 mfma32(h8 a, h8 b, fx4 c) {
  return __builtin_amdgcn_mfma_f32_16x16x32_f16(a, b, c, 0, 0, 0);
}

// LDS tiles: [row][64 hf] = 128B rows, XOR-swizzled at 16B granularity:
// LDS 16B-granule gd holds global granule gd ^ (row&7); read side applies same XOR.
DEVI h8 ld16(const hf* base, int row, int g16) {
  int off = (row * 128 + (g16 << 4)) ^ ((row & 7) << 4);
  return *(const h8*)((const char*)base + off);
}
DEVI h4 ld8(const hf* base, int row, int g8) {
  int off = (row * 128 + (g8 << 3)) ^ ((row & 7) << 4);
  return *(const h4*)((const char*)base + off);
}

// ---------------- weight cast + transpose: W[K][N] f32 -> Wt[N][K] f16 ----------
__global__ __launch_bounds__(256) void k_wcast(const float* __restrict__ W, hf* __restrict__ Wt,
                                               int K, int N) {
  __shared__ float ls[64][65];
  int kt = blockIdx.x, nt = blockIdx.y, t = threadIdx.x;
  int c4 = (t & 15) * 4, r0 = t >> 4;
#pragma unroll
  for (int i = 0; i < 4; ++i) {
    int row = i * 16 + r0;
    fx4 v = *(const fx4*)(W + (size_t)(kt * 64 + row) * N + nt * 64 + c4);
    ls[row][c4 + 0] = v[0]; ls[row][c4 + 1] = v[1];
    ls[row][c4 + 2] = v[2]; ls[row][c4 + 3] = v[3];
  }
  __syncthreads();
  int cc = t >> 4, kk4 = (t & 15) * 4;
#pragma unroll
  for (int i = 0; i < 4; ++i) {
    int nn = i * 16 + cc;
    h4 p = {(hf)ls[kk4 + 0][nn], (hf)ls[kk4 + 1][nn], (hf)ls[kk4 + 2][nn], (hf)ls[kk4 + 3][nn]};
    *(h4*)(Wt + (size_t)(nt * 64 + nn) * K + kt * 64 + kk4) = p;
  }
}

// ---------------- rope table: tab[t][j] = (cos, sin) interleaved, 2048 x 32 -----
__global__ __launch_bounds__(256) void k_table(float* __restrict__ tab) {
  int idx = blockIdx.x * 256 + threadIdx.x;  // 65536
  int tt = idx >> 5, j = idx & 31;
  double e = pow(21.0, (double)j / 31.0) - 1.0;   // 10^(j*log10(21)/31) - 1
  float bf = (float)(0.2 * e);
  float fr = (float)tt * bf;                       // fp32 product like reference
  double d = (double)fr;
  float2 cs = make_float2((float)cos(d), (float)sin(d));
  ((float2*)tab)[idx] = cs;
}

// ---------------- dual rmsnorm (shared mean-square), compact kv rows ------------
__global__ __launch_bounds__(256) void k_dualnorm(const float* __restrict__ x,
                                                  const float* __restrict__ wq,
                                                  const float* __restrict__ wkv,
                                                  hf* __restrict__ xqn, hf* __restrict__ xkvc) {
  int row = blockIdx.x, t = threadIdx.x;
  const fx4* xr = (const fx4*)(x + (size_t)row * 1024);
  fx4 v = xr[t];
  float ss = v[0] * v[0] + v[1] * v[1] + v[2] * v[2] + v[3] * v[3];
#pragma unroll
  for (int m = 1; m <= 32; m <<= 1) ss += __shfl_xor(ss, m);
  __shared__ float red[4];
  if ((t & 63) == 0) red[t >> 6] = ss;
  __syncthreads();
  float r = rsqrtf((red[0] + red[1] + red[2] + red[3]) * (1.0f / 1024.0f) + EPSF);
  fx4 a = ((const fx4*)wq)[t];
  h4 oq = {(hf)(v[0] * r * a[0]), (hf)(v[1] * r * a[1]), (hf)(v[2] * r * a[2]), (hf)(v[3] * r * a[3])};
  *(h4*)(xqn + (size_t)row * 1024 + t * 4) = oq;
  int c = row & 2047;
  if ((c & 3) == 0) {
    fx4 bk = ((const fx4*)wkv)[t];
    int crow = (row >> 11) * 512 + (c >> 2);
    h4 ok = {(hf)(v[0] * r * bk[0]), (hf)(v[1] * r * bk[1]), (hf)(v[2] * r * bk[2]), (hf)(v[3] * r * bk[3])};
    *(h4*)(xkvc + (size_t)crow * 1024 + t * 4) = ok;
  }
}

// ---------------- GEMM: out[M][N] = A[M][K] @ Bt[N][K]^T + bias ------------------
// 128x128 tile, BK=64, 16x16x32 MFMA, double-buffered LDS, counted-vmcnt 2-phase.
// EPI 0: f16 row-major   EPI 1: kv special (k half row-major, v half -> vT)   EPI 2: f32 row-major
template <int EPI>
__global__ __launch_bounds__(256) void k_gemm(const hf* __restrict__ A, const hf* __restrict__ Bt,
                                              const float* __restrict__ bias, void* __restrict__ outp,
                                              int M, int N, int K, int MB, hf* __restrict__ vt) {
  __shared__ alignas(16) hf lsA[2][128 * 64];
  __shared__ alignas(16) hf lsB[2][128 * 64];
  int t = threadIdx.x, l = t & 63, w = t >> 6, grp = l >> 4, ln = l & 15;
  int bm = blockIdx.x % MB, bn = blockIdx.x / MB;
  int m0 = bm * 128, n0 = bn * 128;
  int wr = w >> 1, wc = w & 1;
  fx4 acc[4][4] = {};
  int nkt = K >> 6;

  auto stage = [&](int kt, int b) {
    int k0 = kt << 6;
#pragma unroll
    for (int p = 0; p < 4; ++p) {
      int ci = p * 256 + t;
      int row = ci >> 3, g = (ci & 7) ^ (row & 7);
      async16(A + (size_t)(m0 + row) * K + k0 + g * 8, (char*)lsA[b] + p * 4096 + w * 1024);
    }
#pragma unroll
    for (int p = 0; p < 4; ++p) {
      int ci = p * 256 + t;
      int row = ci >> 3, g = (ci & 7) ^ (row & 7);
      async16(Bt + (size_t)(n0 + row) * K + k0 + g * 8, (char*)lsB[b] + p * 4096 + w * 1024);
    }
  };

  stage(0, 0);
  for (int kt = 0; kt < nkt; ++kt) {
    int cur = kt & 1;
    if (kt + 1 < nkt) {
      stage(kt + 1, cur ^ 1);
      asm volatile("s_waitcnt vmcnt(8)" ::: "memory");  // current tile landed; next stays in flight
    } else {
      asm volatile("s_waitcnt vmcnt(0)" ::: "memory");
    }
    __builtin_amdgcn_s_barrier();
    __builtin_amdgcn_sched_barrier(0);
    __builtin_amdgcn_s_setprio(1);
#pragma unroll
    for (int kk = 0; kk < 2; ++kk) {
      h8 af[4], bf[4];
#pragma unroll
      for (int i = 0; i < 4; ++i) af[i] = ld16(lsA[cur], wr * 64 + i * 16 + ln, kk * 4 + grp);
#pragma unroll
      for (int i = 0; i < 4; ++i) bf[i] = ld16(lsB[cur], wc * 64 + i * 16 + ln, kk * 4 + grp);
#pragma unroll
      for (int mi = 0; mi < 4; ++mi)
#pragma unroll
        for (int ni = 0; ni < 4; ++ni)
          acc[mi][ni] = mfma32(af[mi], bf[ni], acc[mi][ni]);
    }
    __builtin_amdgcn_s_setprio(0);
    __builtin_amdgcn_sched_barrier(0);
    __builtin_amdgcn_s_barrier();  // WAR: all waves done reading buf[cur] before next overwrite
  }
#pragma unroll
  for (int ni = 0; ni < 4; ++ni) {
    int n = n0 + wc * 64 + ni * 16 + ln;
    float bs = bias[n];
#pragma unroll
    for (int mi = 0; mi < 4; ++mi) {
      int mb_ = m0 + wr * 64 + mi * 16 + grp * 4;
      fx4 v = acc[mi][ni];
      v += bs;
      if constexpr (EPI == 2) {
        float* O = (float*)outp;
#pragma unroll
        for (int r = 0; r < 4; ++r) O[(size_t)(mb_ + r) * N + n] = v[r];
      } else if constexpr (EPI == 0) {
        hf* O = (hf*)outp;
#pragma unroll
        for (int r = 0; r < 4; ++r) O[(size_t)(mb_ + r) * N + n] = (hf)v[r];
      } else {
        if (n < 1024) {  // k half, row-major [2048][1024]
          hf* O = (hf*)outp;
#pragma unroll
          for (int r = 0; r < 4; ++r) O[(size_t)(mb_ + r) * 1024 + n] = (hf)v[r];
        } else {  // v half -> vT[b,h][hd][kc]
          int nv = n - 1024, h = nv >> 6, hd = nv & 63;
          int b = m0 >> 9, kc0 = mb_ & 511;
          h4 pk = {(hf)v[0], (hf)v[1], (hf)v[2], (hf)v[3]};
          *(h4*)(vt + ((size_t)(b * 16 + h) * 64 + hd) * 512 + kc0) = pk;
        }
      }
    }
  }
}

// ---------------- rope + per-head rmsnorm + transpose (q and k variants) --------
template <bool ISQ>
__global__ __launch_bounds__(256) void k_post(const hf* __restrict__ raw, const float* __restrict__ lnw,
                                              const float* __restrict__ tab, hf* __restrict__ outn) {
  int row = blockIdx.x, t = threadIdx.x;
  int h = t >> 4, hd0 = (t & 15) * 4;
  h4 q = ((const h4*)(raw + (size_t)row * 1024))[t];
  float q0 = (float)q[0], q1 = (float)q[1], q2 = (float)q[2], q3 = (float)q[3];
  float ss = q0 * q0 + q1 * q1 + q2 * q2 + q3 * q3;
  ss += __shfl_xor(ss, 1); ss += __shfl_xor(ss, 2);
  ss += __shfl_xor(ss, 4); ss += __shfl_xor(ss, 8);
  // rope preserves pair norms -> ms computable pre-rotation
  float scl = rsqrtf(ss * (1.0f / 64.0f) + EPSF);
  if (ISQ) scl *= QSCALE;
  int b, c, seq;
  if (ISQ) { b = row >> 11; c = row & 2047; seq = c; }
  else     { b = row >> 9;  c = row & 511;  seq = c * 4; }
  fx4 cs = *(const fx4*)(tab + (size_t)seq * 64 + hd0);
  float o0 = q0 * cs[0] - q1 * cs[1];
  float o1 = q0 * cs[1] + q1 * cs[0];
  float o2 = q2 * cs[2] - q3 * cs[3];
  float o3 = q2 * cs[3] + q3 * cs[2];
  fx4 lw = *(const fx4*)(lnw + hd0);
  h4 o = {(hf)(o0 * lw[0] * scl), (hf)(o1 * lw[1] * scl), (hf)(o2 * lw[2] * scl), (hf)(o3 * lw[3] * scl)};
  int rows = ISQ ? 2048 : 512;
  *(h4*)(outn + ((size_t)(b * 16 + h) * rows + c) * 64 + hd0) = o;
}

// ---------------- attention v3: R3 LDS-dbuf skeleton + fixed-max softmax --------
// LDS staging decouples MFMA from memory latency (R7 lesson: direct-global is
// latency-bound at 97us). Single __syncthreads per chunk (R3's 43us structure;
// R5's vmcnt choreography regressed to 54us). Fixed-max softmax (validated R7):
// scores bounded by 11.54 < SMAX=12, so no online max/rescale/vote; l-reduce
// deferred to one shfl pair at the end. XCD swizzle keeps FETCH at ~12MB.
__global__ __launch_bounds__(256) void k_attn(const hf* __restrict__ qn, const hf* __restrict__ kn,
                                              const hf* __restrict__ vt, hf* __restrict__ a) {
  __shared__ alignas(16) hf lsK[2][64 * 64];  // [key][hd] swizzled
  __shared__ alignas(16) hf lsV[2][64 * 64];  // [hd][key] swizzled
  int t = threadIdx.x, l = t & 63, w = t >> 6, grp = l >> 4, ln = l & 15;
  int tile = (blockIdx.x & 7) * (gridDim.x >> 3) + (blockIdx.x >> 3);  // XCD-bijective
  int bq = tile & 15, plane = tile >> 4;
  const hf* qp = qn + (size_t)plane * 2048 * 64;
  const hf* kp = kn + (size_t)plane * 512 * 64;
  const hf* vp = vt + (size_t)plane * 64 * 512;
  int q0 = bq * 128 + w * 32;

  auto stageKV = [&](int ch, int b) {
    int kc0 = ch * 64;
#pragma unroll
    for (int p = 0; p < 2; ++p) {
      int ci = p * 256 + t;
      int row = ci >> 3, g = (ci & 7) ^ (row & 7);
      async16(kp + (size_t)(kc0 + row) * 64 + g * 8, (char*)lsK[b] + p * 4096 + w * 1024);
    }
#pragma unroll
    for (int p = 0; p < 2; ++p) {
      int ci = p * 256 + t;
      int row = ci >> 3, g = (ci & 7) ^ (row & 7);
      async16(vp + (size_t)row * 512 + kc0 + g * 8, (char*)lsV[b] + p * 4096 + w * 1024);
    }
  };

  stageKV(0, 0);

  h8 qf[2][2];
#pragma unroll
  for (int mf = 0; mf < 2; ++mf)
#pragma unroll
    for (int kk = 0; kk < 2; ++kk)
      qf[mf][kk] = *(const h8*)(qp + (size_t)(q0 + mf * 16 + ln) * 64 + kk * 32 + grp * 8);

  fx4 o[4][2] = {};
  float lsum[2] = {0.f, 0.f};
  __syncthreads();

  for (int ch = 0; ch < 8; ++ch) {
    int cur = ch & 1;
    if (ch < 7) stageKV(ch + 1, cur ^ 1);
    __builtin_amdgcn_sched_barrier(0);

    // QK^T: s[kt][mf] holds S[key = kt*16+grp*4+j][q = ln]
    fx4 s[4][2] = {};
#pragma unroll
    for (int kk = 0; kk < 2; ++kk) {
      h8 kf[4];
#pragma unroll
      for (int kt = 0; kt < 4; ++kt) kf[kt] = ld16(lsK[cur], kt * 16 + ln, kk * 4 + grp);
#pragma unroll
      for (int kt = 0; kt < 4; ++kt)
#pragma unroll
        for (int mf = 0; mf < 2; ++mf)
          s[kt][mf] = mfma32(kf[kt], qf[mf][kk], s[kt][mf]);
    }

    // fixed-max softmax: pure elementwise, no cross-lane traffic
    h4 pf[4][2];
#pragma unroll
    for (int kt = 0; kt < 4; ++kt)
#pragma unroll
      for (int mf = 0; mf < 2; ++mf) {
        fx4 sv = s[kt][mf];
        float e0 = __builtin_amdgcn_exp2f(sv[0] - SMAX);
        float e1 = __builtin_amdgcn_exp2f(sv[1] - SMAX);
        float e2 = __builtin_amdgcn_exp2f(sv[2] - SMAX);
        float e3 = __builtin_amdgcn_exp2f(sv[3] - SMAX);
        lsum[mf] += (e0 + e1) + (e2 + e3);
        h4 tp = {(hf)e0, (hf)e1, (hf)e2, (hf)e3};
        pf[kt][mf] = tp;
      }

    // PV: o[nh][mf] += V^T-frag x P-frag (P layout natively matches mfma16 B)
#pragma unroll
    for (int ks = 0; ks < 4; ++ks) {
      h4 vf[4];
#pragma unroll
      for (int nh = 0; nh < 4; ++nh) vf[nh] = ld8(lsV[cur], nh * 16 + ln, ks * 4 + grp);
#pragma unroll
      for (int nh = 0; nh < 4; ++nh)
#pragma unroll
        for (int mf = 0; mf < 2; ++mf)
          o[nh][mf] = mfma16(vf[nh], pf[ks][mf], o[nh][mf]);
    }
    __syncthreads();  // prefetch landed + all reads of buf[cur] done
  }

  int b = plane >> 4, h = plane & 15;
#pragma unroll
  for (int mf = 0; mf < 2; ++mf) {
    float p2 = lsum[mf];
    p2 += __shfl_xor(p2, 16);
    p2 += __shfl_xor(p2, 32);
    float inv = 1.0f / p2;
    int cpos = q0 + mf * 16 + ln;
    size_t rowo = ((size_t)b * 2048 + cpos) * 1024;
#pragma unroll
    for (int nh = 0; nh < 4; ++nh) {
      h4 pk = {(hf)(o[nh][mf][0] * inv), (hf)(o[nh][mf][1] * inv),
               (hf)(o[nh][mf][2] * inv), (hf)(o[nh][mf][3] * inv)};
      *(h4*)(a + rowo + h * 64 + nh * 16 + grp * 4) = pk;
    }
  }
}

extern "C" void kernel_launch(void* const* d_in, const int* in_sizes, int n_in,
                              void* d_out, int out_size, void* d_ws, size_t ws_size,
                              hipStream_t stream) {
  (void)in_sizes; (void)n_in; (void)out_size; (void)ws_size;
  const float* x      = (const float*)d_in[0];
  const float* rmsq_w = (const float*)d_in[1];
  const float* q_w    = (const float*)d_in[2];
  const float* q_b    = (const float*)d_in[3];
  const float* rmskv_w= (const float*)d_in[4];
  const float* kv_w   = (const float*)d_in[5];
  const float* kv_b   = (const float*)d_in[6];
  const float* ln_w   = (const float*)d_in[7];
  const float* out_w  = (const float*)d_in[8];
  const float* out_b  = (const float*)d_in[9];

  char* ws = (char*)d_ws;
  hf* wqT   = (hf*)(ws + (size_t)0);           // 2 MB  [1024][1024]
  hf* wkvT  = (hf*)(ws + ((size_t)2 << 20));   // 4 MB  [2048][1024]
  hf* woT   = (hf*)(ws + ((size_t)6 << 20));   // 2 MB
  float* tab= (float*)(ws + ((size_t)8 << 20));// 0.5 MB
  hf* xqn   = (hf*)(ws + ((size_t)9 << 20));   // 16 MB, reused as qn
  hf* qn    = xqn;
  hf* xkvc  = (hf*)(ws + ((size_t)25 << 20));  // 4 MB
  hf* qraw  = (hf*)(ws + ((size_t)29 << 20));  // 16 MB, reused as attn out
  hf* abuf  = qraw;
  hf* kraw  = (hf*)(ws + ((size_t)45 << 20));  // 4 MB
  hf* kn    = (hf*)(ws + ((size_t)49 << 20));  // 4 MB
  hf* vt    = (hf*)(ws + ((size_t)53 << 20));  // 4 MB

  k_wcast<<<dim3(16, 16), 256, 0, stream>>>(q_w,   wqT,  1024, 1024);
  k_wcast<<<dim3(16, 32), 256, 0, stream>>>(kv_w,  wkvT, 1024, 2048);
  k_wcast<<<dim3(16, 16), 256, 0, stream>>>(out_w, woT,  1024, 1024);
  k_table<<<256, 256, 0, stream>>>(tab);
  k_dualnorm<<<8192, 256, 0, stream>>>(x, rmsq_w, rmskv_w, xqn, xkvc);
  k_gemm<0><<<64 * 8, 256, 0, stream>>>(xqn, wqT, q_b, qraw, 8192, 1024, 1024, 64, nullptr);
  k_gemm<1><<<16 * 16, 256, 0, stream>>>(xkvc, wkvT, kv_b, kraw, 2048, 2048, 1024, 16, vt);
  k_post<true><<<8192, 256, 0, stream>>>(qraw, ln_w, tab, qn);
  k_post<false><<<2048, 256, 0, stream>>>(kraw, ln_w, tab, kn);
  k_attn<<<1024, 256, 0, stream>>>(qn, kn, vt, abuf);
  k_gemm<2><<<64 * 8, 256, 0, stream>>>(abuf, woT, out_b, d_out, 8192, 1024, 1024, 64, nullptr);
}